// Round 2
// baseline (4425.861 us; speedup 1.0000x reference)
//
#include <hip/hip_runtime.h>

#define NB 256
#define NT 1000
#define ND 64
#define NH 128

__device__ __forceinline__ float sigmoid_f(float x) {
    float e = __builtin_amdgcn_exp2f(-1.4426950408889634f * x);
    return __builtin_amdgcn_rcpf(1.0f + e);
}
__device__ __forceinline__ float tanh_f(float x) {
    float e = __builtin_amdgcn_exp2f(-2.8853900817779268f * x);
    return 2.0f * __builtin_amdgcn_rcpf(1.0f + e) - 1.0f;
}

__global__ __launch_bounds__(512, 2) void gruode_fused(
    const float* __restrict__ x,      // (B,T,D)
    const float* __restrict__ tps,    // (T)
    const int*   __restrict__ mask,   // (B,T)
    const float* __restrict__ W_ih,   // (384,64)
    const float* __restrict__ W_hh,   // (384,128)
    const float* __restrict__ b_ih,   // (384)
    const float* __restrict__ b_hh,   // (384)
    const float* __restrict__ nW1,    // (128,128)
    const float* __restrict__ nb1,    // (128)
    const float* __restrict__ nW2,    // (128,128)
    const float* __restrict__ nb2,    // (128)
    const float* __restrict__ W_out,  // (128,128)
    const float* __restrict__ b_out,  // (128)
    float* __restrict__ out)          // (B,128)
{
    __shared__ float sh_h[2][NH];
    __shared__ float sh_tmp[NH];
    __shared__ float sh_ode[NH];
    __shared__ float sh_dt[NT];
    __shared__ int   sh_m[NT];

    const int tid = threadIdx.x;
    const int j   = tid >> 2;   // output row 0..127
    const int q   = tid & 3;    // K-quarter
    const int kb  = q * 32;     // K base (floats) for H-dots
    const int kbi = q * 16;     // K base (floats) for D-dots
    const int b   = blockIdx.x;

    // Rotated column offset: for unroll index i, q-groups hit distinct banks.
    // bank = ((kb + w*4)*4/4) % 32 = (w*4) % 32 with w=(i+2q)&7 -> distinct per q.
#define ROTC(i) (kb + ((((i) + 2 * q) & 7) << 2))

    // ---- stage all weights into registers (one-time), pre-rotated ----
    float4 w1v[8], w2v[8], whr[8], whz[8], whn[8];
    float4 wir[4], wiz[4], win[4];
#pragma unroll
    for (int i = 0; i < 8; ++i) {
        const int c = ROTC(i);
        w1v[i] = *(const float4*)(nW1  + (j      )*NH + c);
        w2v[i] = *(const float4*)(nW2  + (j      )*NH + c);
        whr[i] = *(const float4*)(W_hh + (j      )*NH + c);
        whz[i] = *(const float4*)(W_hh + (j + 128)*NH + c);
        whn[i] = *(const float4*)(W_hh + (j + 256)*NH + c);
    }
#pragma unroll
    for (int i = 0; i < 4; ++i) {
        wir[i] = *(const float4*)(W_ih + (j      )*ND + kbi + i*4);
        wiz[i] = *(const float4*)(W_ih + (j + 128)*ND + kbi + i*4);
        win[i] = *(const float4*)(W_ih + (j + 256)*ND + kbi + i*4);
    }
    const float bb1   = nb1[j];
    const float bb2   = nb2[j];
    const float brz_r = b_ih[j]       + b_hh[j];
    const float brz_z = b_ih[j + 128] + b_hh[j + 128];
    const float bin_n = b_ih[j + 256];
    const float bhn_n = b_hh[j + 256];

    // ---- stage dt / mask into LDS; init h ----
    for (int s = tid; s < NT; s += 512) {
        sh_dt[s] = (s == 0) ? 0.0f : (tps[s] - tps[s - 1]);
        sh_m[s]  = mask[b * NT + s];
    }
    if (tid < NH) sh_h[0][tid] = 0.0f;
    __syncthreads();

    float hlast = 0.0f;
    int   seen  = 0;

    for (int s = 0; s < NT; ++s) {
        const int   cur = s & 1, nxt = cur ^ 1;
        const int   m   = sh_m[s];                 // uniform per block
        const float dte = seen ? sh_dt[s] : 0.0f;  // r_fill freeze (uniform)

        // prefetch x_t (latency hidden under node stages)
        const float* xr = x + ((size_t)b * NT + s) * ND + kbi;
        float4 xv[4];
#pragma unroll
        for (int i = 0; i < 4; ++i) xv[i] = *(const float4*)(xr + i*4);

        const float hj = sh_h[cur][j];
        float hode_j;
        const float* hsrc;

        if (dte != 0.0f) {
            // stage 1: tmp = tanh(W1 h + b1)
            float a1 = 0.0f;
#pragma unroll
            for (int i = 0; i < 8; ++i) {
                const float4 hv = *(const float4*)(&sh_h[cur][0] + ROTC(i));
                a1 += w1v[i].x*hv.x + w1v[i].y*hv.y + w1v[i].z*hv.z + w1v[i].w*hv.w;
            }
            a1 += __shfl_xor(a1, 1);
            a1 += __shfl_xor(a1, 2);
            if (q == 0) sh_tmp[j] = tanh_f(a1 + bb1);
            __syncthreads();

            // stage 2: h_ode = h + dt * (W2 tmp + b2)
            float a2 = 0.0f;
#pragma unroll
            for (int i = 0; i < 8; ++i) {
                const float4 hv = *(const float4*)(sh_tmp + ROTC(i));
                a2 += w2v[i].x*hv.x + w2v[i].y*hv.y + w2v[i].z*hv.z + w2v[i].w*hv.w;
            }
            a2 += __shfl_xor(a2, 1);
            a2 += __shfl_xor(a2, 2);
            hode_j = hj + dte * (a2 + bb2);
            if (q == 0) sh_ode[j] = hode_j;
            __syncthreads();
            hsrc = sh_ode;
        } else {
            hode_j = hj;
            hsrc = &sh_h[cur][0];
        }

        // stage 3: GRU cell
        float ar = 0.0f, az = 0.0f, an = 0.0f;
#pragma unroll
        for (int i = 0; i < 8; ++i) {
            const float4 hv = *(const float4*)(hsrc + ROTC(i));
            ar += whr[i].x*hv.x + whr[i].y*hv.y + whr[i].z*hv.z + whr[i].w*hv.w;
            az += whz[i].x*hv.x + whz[i].y*hv.y + whz[i].z*hv.z + whz[i].w*hv.w;
            an += whn[i].x*hv.x + whn[i].y*hv.y + whn[i].z*hv.z + whn[i].w*hv.w;
        }
        float gr = 0.0f, gz = 0.0f, gn = 0.0f;
#pragma unroll
        for (int i = 0; i < 4; ++i) {
            gr += wir[i].x*xv[i].x + wir[i].y*xv[i].y + wir[i].z*xv[i].z + wir[i].w*xv[i].w;
            gz += wiz[i].x*xv[i].x + wiz[i].y*xv[i].y + wiz[i].z*xv[i].z + wiz[i].w*xv[i].w;
            gn += win[i].x*xv[i].x + win[i].y*xv[i].y + win[i].z*xv[i].z + win[i].w*xv[i].w;
        }
        float sr = ar + gr, sz = az + gz;
        sr += __shfl_xor(sr, 1); sr += __shfl_xor(sr, 2);
        sz += __shfl_xor(sz, 1); sz += __shfl_xor(sz, 2);
        an += __shfl_xor(an, 1); an += __shfl_xor(an, 2);
        gn += __shfl_xor(gn, 1); gn += __shfl_xor(gn, 2);

        const float r = sigmoid_f(sr + brz_r);
        const float z = sigmoid_f(sz + brz_z);
        const float n = tanh_f(gn + bin_n + r * (an + bhn_n));
        const float hnew = m ? ((1.0f - z) * n + z * hode_j) : hode_j;

        if (q == 0) sh_h[nxt][j] = hnew;   // ping-pong: no pre-write barrier needed
        if (m) hlast = hnew;
        seen |= m;
        __syncthreads();                   // h[nxt] visible for next step
    }

    // epilogue: out = W_out @ h_last + b_out
    if (q == 0) sh_tmp[j] = hlast;
    __syncthreads();
    float ao = 0.0f;
#pragma unroll
    for (int i = 0; i < 8; ++i) {
        const int c = ROTC(i);
        const float4 wv = *(const float4*)(W_out + j*NH + c);
        const float4 hv = *(const float4*)(sh_tmp + c);
        ao += wv.x*hv.x + wv.y*hv.y + wv.z*hv.z + wv.w*hv.w;
    }
    ao += __shfl_xor(ao, 1);
    ao += __shfl_xor(ao, 2);
    if (q == 0) out[b*NH + j] = ao + b_out[j];
}

extern "C" void kernel_launch(void* const* d_in, const int* in_sizes, int n_in,
                              void* d_out, int out_size, void* d_ws, size_t ws_size,
                              hipStream_t stream) {
    const float* x     = (const float*)d_in[0];
    const float* tps   = (const float*)d_in[1];
    const int*   mask  = (const int*)  d_in[2];
    const float* W_ih  = (const float*)d_in[3];
    const float* W_hh  = (const float*)d_in[4];
    const float* b_ih  = (const float*)d_in[5];
    const float* b_hh  = (const float*)d_in[6];
    const float* nW1   = (const float*)d_in[7];
    const float* nb1   = (const float*)d_in[8];
    const float* nW2   = (const float*)d_in[9];
    const float* nb2   = (const float*)d_in[10];
    const float* W_out = (const float*)d_in[11];
    const float* b_out = (const float*)d_in[12];
    float* out = (float*)d_out;

    gruode_fused<<<dim3(NB), dim3(512), 0, stream>>>(
        x, tps, mask, W_ih, W_hh, b_ih, b_hh,
        nW1, nb1, nW2, nb2, W_out, b_out, out);
}

// Round 3
// 1333.997 us; speedup vs baseline: 3.3177x; 3.3177x over previous
//
#include <hip/hip_runtime.h>

#define NB 256
#define NT 1000
#define ND 64
#define NH 128

typedef _Float16 h2 __attribute__((ext_vector_type(2)));

__device__ __forceinline__ uint pk(float a, float b) {
#if __has_builtin(__builtin_amdgcn_cvt_pkrtz)
    return __builtin_bit_cast(uint, __builtin_amdgcn_cvt_pkrtz(a, b));
#else
    h2 h; h.x = (_Float16)a; h.y = (_Float16)b;
    return __builtin_bit_cast(uint, h);
#endif
}
__device__ __forceinline__ float fdot2u(uint a, uint b, float c) {
#if __has_builtin(__builtin_amdgcn_fdot2)
    return __builtin_amdgcn_fdot2(__builtin_bit_cast(h2, a),
                                  __builtin_bit_cast(h2, b), c, false);
#else
    h2 ha = __builtin_bit_cast(h2, a), hb = __builtin_bit_cast(h2, b);
    return c + (float)ha.x * (float)hb.x + (float)ha.y * (float)hb.y;
#endif
}
__device__ __forceinline__ float sigmoid_f(float x) {
    float e = __builtin_amdgcn_exp2f(-1.4426950408889634f * x);
    return __builtin_amdgcn_rcpf(1.0f + e);
}
__device__ __forceinline__ float tanh_f(float x) {
    float e = __builtin_amdgcn_exp2f(-2.8853900817779268f * x);
    return 2.0f * __builtin_amdgcn_rcpf(1.0f + e) - 1.0f;
}

// load 8 consecutive f32 weights, pack to 4 f16x2 regs
__device__ __forceinline__ void ld8(const float* p, uint* d) {
    const float4 A = *(const float4*)p;
    const float4 B = *(const float4*)(p + 4);
    d[0] = pk(A.x, A.y); d[1] = pk(A.z, A.w);
    d[2] = pk(B.x, B.y); d[3] = pk(B.z, B.w);
}

#define PIN(v) asm volatile("" : "+v"(v))

__global__ __launch_bounds__(512, 2) void gruode_fused(
    const float* __restrict__ x,      // (B,T,D)
    const float* __restrict__ tps,    // (T)
    const int*   __restrict__ mask,   // (B,T)
    const float* __restrict__ W_ih,   // (384,64)
    const float* __restrict__ W_hh,   // (384,128)
    const float* __restrict__ b_ih,   // (384)
    const float* __restrict__ b_hh,   // (384)
    const float* __restrict__ nW1,    // (128,128)
    const float* __restrict__ nb1,    // (128)
    const float* __restrict__ nW2,    // (128,128)
    const float* __restrict__ nb2,    // (128)
    const float* __restrict__ W_out,  // (128,128)
    const float* __restrict__ b_out,  // (128)
    float* __restrict__ out)          // (B,128)
{
    __shared__ __align__(16) _Float16 sh_h[2][NH];
    __shared__ __align__(16) _Float16 sh_tmp[NH];
    __shared__ __align__(16) _Float16 sh_ode[NH];
    __shared__ float sh_eo[NH];
    __shared__ float sh_dt[NT];
    __shared__ int   sh_m[NT];

    const int tid = threadIdx.x;
    const int j   = tid >> 2;   // output row 0..127
    const int q   = tid & 3;    // K-quarter
    const int kb  = q * 32;     // f32/f16-element K base for H-dots
    const int kbi = q * 16;     // K base for D-dots
    const int b   = blockIdx.x;

    // ---- stage all weights into f16x2 registers (one-time), pre-rotated ----
    // chunk i reads cols [kb + w*8, +8) with w=(i+(q>>1))&3 -> per-instr the 4
    // q-groups land on disjoint LDS bank quads at step time.
    uint w1[4][4], w2[4][4], whr[4][4], whz[4][4], whn[4][4];
    uint wir[8], wiz[8], win[8];
#pragma unroll
    for (int i = 0; i < 4; ++i) {
        const int c = kb + (((i + (q >> 1)) & 3) << 3);
        ld8(nW1  + (j      )*NH + c, w1[i]);
        ld8(nW2  + (j      )*NH + c, w2[i]);
        ld8(W_hh + (j      )*NH + c, whr[i]);
        ld8(W_hh + (j + 128)*NH + c, whz[i]);
        ld8(W_hh + (j + 256)*NH + c, whn[i]);
    }
    ld8(W_ih + (j      )*ND + kbi,     wir);
    ld8(W_ih + (j      )*ND + kbi + 8, wir + 4);
    ld8(W_ih + (j + 128)*ND + kbi,     wiz);
    ld8(W_ih + (j + 128)*ND + kbi + 8, wiz + 4);
    ld8(W_ih + (j + 256)*ND + kbi,     win);
    ld8(W_ih + (j + 256)*ND + kbi + 8, win + 4);
    float bb1   = nb1[j];
    float bb2   = nb2[j];
    float brz_r = b_ih[j]       + b_hh[j];
    float brz_z = b_ih[j + 128] + b_hh[j + 128];
    float bin_n = b_ih[j + 256];
    float bhn_n = b_hh[j + 256];

    // pin: values become asm results -> cannot be re-materialized via reload
#pragma unroll
    for (int i = 0; i < 4; ++i)
#pragma unroll
        for (int k = 0; k < 4; ++k) {
            PIN(w1[i][k]); PIN(w2[i][k]);
            PIN(whr[i][k]); PIN(whz[i][k]); PIN(whn[i][k]);
        }
#pragma unroll
    for (int k = 0; k < 8; ++k) { PIN(wir[k]); PIN(wiz[k]); PIN(win[k]); }
    PIN(bb1); PIN(bb2); PIN(brz_r); PIN(brz_z); PIN(bin_n); PIN(bhn_n);

    // ---- stage dt / mask into LDS; init h ----
    for (int s = tid; s < NT; s += 512) {
        sh_dt[s] = (s == 0) ? 0.0f : (tps[s] - tps[s - 1]);
        sh_m[s]  = mask[b * NT + s];
    }
    if (tid < NH) sh_h[0][tid] = (_Float16)0.0f;
    __syncthreads();

    float hlast = 0.0f;
    int   seen  = 0;

    for (int s = 0; s < NT; ++s) {
        const int   cur = s & 1, nxt = cur ^ 1;
        const int   m   = sh_m[s];                 // uniform per block
        const float dte = seen ? sh_dt[s] : 0.0f;  // r_fill freeze (uniform)

        // prefetch + pack x_t
        const float* xr = x + ((size_t)b * NT + s) * ND + kbi;
        const float4 x0 = *(const float4*)(xr);
        const float4 x1 = *(const float4*)(xr + 4);
        const float4 x2 = *(const float4*)(xr + 8);
        const float4 x3 = *(const float4*)(xr + 12);
        uint xh[8];
        xh[0] = pk(x0.x, x0.y); xh[1] = pk(x0.z, x0.w);
        xh[2] = pk(x1.x, x1.y); xh[3] = pk(x1.z, x1.w);
        xh[4] = pk(x2.x, x2.y); xh[5] = pk(x2.z, x2.w);
        xh[6] = pk(x3.x, x3.y); xh[7] = pk(x3.z, x3.w);

        const float hj = (float)sh_h[cur][j];
        float hode_j;
        const _Float16* hsrc;

        if (dte != 0.0f) {
            // stage 1: tmp = tanh(W1 h + b1)
            float a1 = 0.0f;
#pragma unroll
            for (int i = 0; i < 4; ++i) {
                const int w_ = (i + (q >> 1)) & 3;
                const uint4 hv = *(const uint4*)(&sh_h[cur][0] + kb + w_*8);
                a1 = fdot2u(w1[i][0], hv.x, a1);
                a1 = fdot2u(w1[i][1], hv.y, a1);
                a1 = fdot2u(w1[i][2], hv.z, a1);
                a1 = fdot2u(w1[i][3], hv.w, a1);
            }
            a1 += __shfl_xor(a1, 1);
            a1 += __shfl_xor(a1, 2);
            if (q == 0) sh_tmp[j] = (_Float16)tanh_f(a1 + bb1);
            __syncthreads();

            // stage 2: h_ode = h + dt * (W2 tmp + b2)
            float a2 = 0.0f;
#pragma unroll
            for (int i = 0; i < 4; ++i) {
                const int w_ = (i + (q >> 1)) & 3;
                const uint4 hv = *(const uint4*)(sh_tmp + kb + w_*8);
                a2 = fdot2u(w2[i][0], hv.x, a2);
                a2 = fdot2u(w2[i][1], hv.y, a2);
                a2 = fdot2u(w2[i][2], hv.z, a2);
                a2 = fdot2u(w2[i][3], hv.w, a2);
            }
            a2 += __shfl_xor(a2, 1);
            a2 += __shfl_xor(a2, 2);
            hode_j = hj + dte * (a2 + bb2);
            if (q == 0) sh_ode[j] = (_Float16)hode_j;
            __syncthreads();
            hsrc = sh_ode;
        } else {
            hode_j = hj;
            hsrc = &sh_h[cur][0];
        }

        // stage 3: GRU cell
        float ar = 0.0f, az = 0.0f, an = 0.0f;
#pragma unroll
        for (int i = 0; i < 4; ++i) {
            const int w_ = (i + (q >> 1)) & 3;
            const uint4 hv = *(const uint4*)(hsrc + kb + w_*8);
            ar = fdot2u(whr[i][0], hv.x, ar);
            ar = fdot2u(whr[i][1], hv.y, ar);
            ar = fdot2u(whr[i][2], hv.z, ar);
            ar = fdot2u(whr[i][3], hv.w, ar);
            az = fdot2u(whz[i][0], hv.x, az);
            az = fdot2u(whz[i][1], hv.y, az);
            az = fdot2u(whz[i][2], hv.z, az);
            az = fdot2u(whz[i][3], hv.w, az);
            an = fdot2u(whn[i][0], hv.x, an);
            an = fdot2u(whn[i][1], hv.y, an);
            an = fdot2u(whn[i][2], hv.z, an);
            an = fdot2u(whn[i][3], hv.w, an);
        }
        float gr = 0.0f, gz = 0.0f, gn = 0.0f;
#pragma unroll
        for (int k = 0; k < 8; ++k) {
            gr = fdot2u(wir[k], xh[k], gr);
            gz = fdot2u(wiz[k], xh[k], gz);
            gn = fdot2u(win[k], xh[k], gn);
        }
        float sr = ar + gr, sz = az + gz;
        sr += __shfl_xor(sr, 1); sr += __shfl_xor(sr, 2);
        sz += __shfl_xor(sz, 1); sz += __shfl_xor(sz, 2);
        an += __shfl_xor(an, 1); an += __shfl_xor(an, 2);
        gn += __shfl_xor(gn, 1); gn += __shfl_xor(gn, 2);

        const float r = sigmoid_f(sr + brz_r);
        const float z = sigmoid_f(sz + brz_z);
        const float n = tanh_f(gn + bin_n + r * (an + bhn_n));
        const float hnew = m ? ((1.0f - z) * n + z * hode_j) : hode_j;

        if (q == 0) sh_h[nxt][j] = (_Float16)hnew;  // ping-pong write
        if (m) hlast = hnew;
        seen |= m;
        __syncthreads();
    }

    // epilogue (f32): out = W_out @ h_last + b_out
    if (q == 0) sh_eo[j] = hlast;
    __syncthreads();
    float ao = 0.0f;
#pragma unroll
    for (int i = 0; i < 8; ++i) {
        const int c = kb + ((((i) + 2 * q) & 7) << 2);
        const float4 wv = *(const float4*)(W_out + j*NH + c);
        const float4 hv = *(const float4*)(sh_eo + c);
        ao += wv.x*hv.x + wv.y*hv.y + wv.z*hv.z + wv.w*hv.w;
    }
    ao += __shfl_xor(ao, 1);
    ao += __shfl_xor(ao, 2);
    if (q == 0) out[b*NH + j] = ao + b_out[j];
}

extern "C" void kernel_launch(void* const* d_in, const int* in_sizes, int n_in,
                              void* d_out, int out_size, void* d_ws, size_t ws_size,
                              hipStream_t stream) {
    const float* x     = (const float*)d_in[0];
    const float* tps   = (const float*)d_in[1];
    const int*   mask  = (const int*)  d_in[2];
    const float* W_ih  = (const float*)d_in[3];
    const float* W_hh  = (const float*)d_in[4];
    const float* b_ih  = (const float*)d_in[5];
    const float* b_hh  = (const float*)d_in[6];
    const float* nW1   = (const float*)d_in[7];
    const float* nb1   = (const float*)d_in[8];
    const float* nW2   = (const float*)d_in[9];
    const float* nb2   = (const float*)d_in[10];
    const float* W_out = (const float*)d_in[11];
    const float* b_out = (const float*)d_in[12];
    float* out = (float*)d_out;

    gruode_fused<<<dim3(NB), dim3(512), 0, stream>>>(
        x, tps, mask, W_ih, W_hh, b_ih, b_hh,
        nW1, nb1, nW2, nb2, W_out, b_out, out);
}